// Round 1
// baseline (126.171 us; speedup 1.0000x reference)
//
#include <hip/hip_runtime.h>
#include <hip/hip_bf16.h>
#include <math.h>

// TransitionLoss on MI355X.
// Key facts: masks partition the 256 columns per anchor; tr[r,c] only needed
// for r,c in R with inner sum over K; sim is symmetric so one gathered
// submatrix S = sim[R x K] feeds both masked softmaxes.

constexpr int kB  = 256;   // batch
constexpr int kD  = 512;   // feature dim
constexpr int kNT = 512;   // threads per anchor block (8 waves)

constexpr int A_CAP = 16512;  // floats: max nR*SK  (nR=128,nK=128 -> 128*129)
constexpr int B_CAP = 16896;  // floats: max nK*SR  (nK=127,nR=129 -> 127*132=16764)

// LDS bytes: (A_CAP + B_CAP + 4*256 stats + 16 red)*4 + idx 2048 + cat 256 + cnt 16 + lossAcc 4
constexpr int SMEM_BYTES = (A_CAP + B_CAP + 4 * 256 + 16) * 4 + 2048 + 256 + 16 + 4 + 12; // = 140128

// ---------------- sim = f @ f^T (tiled 16x16) ----------------
__global__ void simKernel(const float* __restrict__ f, float* __restrict__ sim) {
  __shared__ float As[16][65];
  __shared__ float Bs[16][65];
  const int tid = threadIdx.x;
  const int tx = tid & 15, ty = tid >> 4;
  const int rowBase = blockIdx.y * 16, colBase = blockIdx.x * 16;
  float acc = 0.f;
  for (int k0 = 0; k0 < kD; k0 += 64) {
    for (int e = tid; e < 1024; e += 256) {
      int r = e >> 6, c = e & 63;
      As[r][c] = f[(rowBase + r) * kD + k0 + c];
      Bs[r][c] = f[(colBase + r) * kD + k0 + c];
    }
    __syncthreads();
#pragma unroll
    for (int kk = 0; kk < 64; kk++) acc = fmaf(As[ty][kk], Bs[tx][kk], acc);
    __syncthreads();
  }
  sim[(rowBase + ty) * kB + colBase + tx] = acc;
}

// ---------------- per-anchor loss ----------------
__global__ __launch_bounds__(kNT)
void anchorKernel(const float* __restrict__ sim, const int* __restrict__ subv,
                  const int* __restrict__ tgtv, float* __restrict__ lossPer) {
  extern __shared__ float smem[];
  float* Sa = smem;               // S, then ea in place (stride SK, odd)
  float* Eb = Sa + A_CAP;         // eb[k][c] (stride SR, mult of 4)
  float* rm = Eb + B_CAP;         // row max   [256]
  float* rs = rm + 256;           // 1/rowsum  [256]
  float* cm = rs + 256;           // col max   [256]
  float* cs = cm + 256;           // 1/colsum  [256]
  float* red = cs + 256;          // wave partials [16]
  unsigned short* idx = (unsigned short*)(red + 16);   // [4][256] index lists
  unsigned char* catL = (unsigned char*)(idx + 1024);  // [256] category
  int* cnt = (int*)(catL + 256);                       // [4]
  float* lossAcc = (float*)(cnt + 4);

  const int i = blockIdx.x;
  const int tid = threadIdx.x;
  const int lane = tid & 63;
  const int wave = tid >> 6;

  const int ti = tgtv[i];
  const int si = subv[i];

  if (tid < kB) {
    bool pos = (tgtv[tid] == ti);
    bool intra = (subv[tid] == si);
    // 0=mpi 1=mpc 2=mni 3=mnc
    catL[tid] = (unsigned char)(pos ? (intra ? 0 : 1) : (intra ? 2 : 3));
  }
  if (tid == 0) *lossAcc = 0.f;
  __syncthreads();

  // ballot-compaction: wave w builds list for category w (ascending order)
  if (wave < 4) {
    int base = 0;
    for (int chunk = 0; chunk < 4; chunk++) {
      int c = (chunk << 6) + lane;
      bool fl = (catL[c] == (unsigned char)wave);
      unsigned long long m = __ballot(fl);
      if (fl) {
        int p = __popcll(m & ((1ull << lane) - 1ull));
        idx[(wave << 8) + base + p] = (unsigned short)c;
      }
      base += __popcll(m);
    }
    if (lane == 0) cnt[wave] = base;
  }
  __syncthreads();

  for (int part = 0; part < 2; part++) {
    // part 0: neg  R=mni K=mnc  f(x)=relu(x-0.2)
    // part 1: pos  R=mpi K=mpc  f(x)=relu(0.5-x)
    const unsigned short* idxR = (part == 0) ? (idx + 512) : idx;
    const unsigned short* idxK = (part == 0) ? (idx + 768) : (idx + 256);
    const int nR = (part == 0) ? cnt[2] : cnt[0];
    const int nK = (part == 0) ? cnt[3] : cnt[1];
    if (nR == 0) continue;  // uniform across block
    int SK = (nK | 1); if (SK < 9) SK = 9;        // odd stride (bank spread)
    int SR = (nR + 3) & ~3; if (SR < 8) SR = 8;   // x4 stride (b128 aligned)

    for (int e = tid; e < nK * SR; e += kNT) Eb[e] = 0.f;

    if (nK > 0) {
      const int tot = nR * nK;
      // gather S[r][k] = sim[idxR[r], idxK[k]]  (symmetric: also = sim[idxK[k], idxR[r]])
      for (int e = tid; e < tot; e += kNT) {
        int r = e / nK, k = e - r * nK;
        Sa[r * SK + k] = sim[(int)idxR[r] * kB + (int)idxK[k]];
      }
      __syncthreads();
      // stats: threads 0..255 do rows, 256..511 do cols (concurrent, read-only)
      if (tid < 256) {
        for (int r = tid; r < nR; r += 256) {
          const float* row = Sa + r * SK;
          float m = -3.4e38f;
          for (int k = 0; k < nK; k++) m = fmaxf(m, row[k]);
          float s = 0.f;
          for (int k = 0; k < nK; k++) s += __expf(row[k] - m);
          rm[r] = m; rs[r] = 1.f / s;
        }
      } else {
        for (int k = tid - 256; k < nK; k += 256) {
          float m = -3.4e38f;
          for (int c = 0; c < nR; c++) m = fmaxf(m, Sa[c * SK + k]);
          float s = 0.f;
          for (int c = 0; c < nR; c++) s += __expf(Sa[c * SK + k] - m);
          cm[k] = m; cs[k] = 1.f / s;
        }
      }
      __syncthreads();
      // eb[k][c] = exp(S[c][k]-cm[k]) * (1/colsum[k])   (ba rows)
      const int totB = nK * nR;
      for (int e = tid; e < totB; e += kNT) {
        int k = e / nR, c = e - k * nR;
        Eb[k * SR + c] = __expf(Sa[c * SK + k] - cm[k]) * cs[k];
      }
      __syncthreads();
      // ea in place: S[r][k] -> exp(S-rm)*1/rowsum   (ab rows)
      for (int e = tid; e < tot; e += kNT) {
        int r = e / nK, k = e - r * nK;
        float v = Sa[r * SK + k];
        Sa[r * SK + k] = __expf(v - rm[r]) * rs[r];
      }
      __syncthreads();
    }

    // tr = ea @ eb over K, tiled 128x128, 512 thr = 32x16 groups, 4x8 per thread
    float partSum = 0.f;
    const int tx = tid & 15;
    const int tyg = tid >> 4;  // 0..31
    for (int r0 = 0; r0 < nR; r0 += 128) {
      for (int c0 = 0; c0 < nR; c0 += 128) {
        const int rbase = r0 + tyg * 4;
        const int cbase = c0 + (tx << 3);
        int aOff[4];
#pragma unroll
        for (int j = 0; j < 4; j++) {
          int rr = rbase + j; if (rr > nR - 1) rr = nR - 1;  // clamp; dup rows discarded
          aOff[j] = rr * SK;
        }
        int cb = cbase; if (cb > SR - 8) cb = SR - 8;        // clamp; dedup via cc>=cbase
        float acc[4][8];
#pragma unroll
        for (int j = 0; j < 4; j++)
#pragma unroll
          for (int jj = 0; jj < 8; jj++) acc[j][jj] = 0.f;
        for (int k = 0; k < nK; k++) {
          const float* ebrow = Eb + k * SR + cb;
          float4 b0 = *(const float4*)(ebrow);
          float4 b1 = *(const float4*)(ebrow + 4);
          float bb0 = b0.x, bb1 = b0.y, bb2 = b0.z, bb3 = b0.w;
          float bb4 = b1.x, bb5 = b1.y, bb6 = b1.z, bb7 = b1.w;
#pragma unroll
          for (int j = 0; j < 4; j++) {
            float a = Sa[aOff[j] + k];
            acc[j][0] = fmaf(a, bb0, acc[j][0]);
            acc[j][1] = fmaf(a, bb1, acc[j][1]);
            acc[j][2] = fmaf(a, bb2, acc[j][2]);
            acc[j][3] = fmaf(a, bb3, acc[j][3]);
            acc[j][4] = fmaf(a, bb4, acc[j][4]);
            acc[j][5] = fmaf(a, bb5, acc[j][5]);
            acc[j][6] = fmaf(a, bb6, acc[j][6]);
            acc[j][7] = fmaf(a, bb7, acc[j][7]);
          }
        }
#pragma unroll
        for (int j = 0; j < 4; j++) {
          int r = rbase + j;
          if (r >= nR) continue;
#pragma unroll
          for (int jj = 0; jj < 8; jj++) {
            int cc = cb + jj;
            if (cc >= cbase && cc < nR) {
              float x = sqrtf(fmaxf(acc[j][jj], 1e-12f));
              partSum += (part == 0) ? fmaxf(x - 0.2f, 0.f) : fmaxf(0.5f - x, 0.f);
            }
          }
        }
      }
    }

    // block reduce -> lossAcc
#pragma unroll
    for (int o = 1; o < 64; o <<= 1) partSum += __shfl_xor(partSum, o, 64);
    if (lane == 0) red[wave] = partSum;
    __syncthreads();
    if (tid == 0) {
      float t = 0.f;
      for (int w = 0; w < kNT / 64; w++) t += red[w];
      *lossAcc += t / (float)(nR * nR);
    }
    __syncthreads();
  }
  if (tid == 0) lossPer[i] = *lossAcc;
}

// ---------------- deterministic final reduce ----------------
__global__ void reduceKernel(const float* __restrict__ lossPer, float* __restrict__ out) {
  const int tid = threadIdx.x;
  float v = lossPer[tid];
#pragma unroll
  for (int o = 1; o < 64; o <<= 1) v += __shfl_xor(v, o, 64);
  __shared__ float r4[4];
  if ((tid & 63) == 0) r4[tid >> 6] = v;
  __syncthreads();
  if (tid == 0) out[0] = (r4[0] + r4[1] + r4[2] + r4[3]) * (1.0f / 256.0f);
}

extern "C" void kernel_launch(void* const* d_in, const int* in_sizes, int n_in,
                              void* d_out, int out_size, void* d_ws, size_t ws_size,
                              hipStream_t stream) {
  (void)in_sizes; (void)n_in; (void)out_size; (void)ws_size;
  const float* feature = (const float*)d_in[0];
  const int* subv = (const int*)d_in[1];
  const int* tgtv = (const int*)d_in[2];
  float* out = (float*)d_out;
  float* sim = (float*)d_ws;            // 256*256 floats
  float* lossPer = sim + kB * kB;       // 256 floats

  // allow >64KB dynamic LDS (idempotent; host-side attribute, graph-safe)
  (void)hipFuncSetAttribute(reinterpret_cast<const void*>(anchorKernel),
                            hipFuncAttributeMaxDynamicSharedMemorySize, SMEM_BYTES);

  simKernel<<<dim3(16, 16), 256, 0, stream>>>(feature, sim);
  anchorKernel<<<dim3(kB), kNT, SMEM_BYTES, stream>>>(sim, subv, tgtv, lossPer);
  reduceKernel<<<1, 256, 0, stream>>>(lossPer, out);
}

// Round 2
// 122.441 us; speedup vs baseline: 1.0305x; 1.0305x over previous
//
#include <hip/hip_runtime.h>
#include <hip/hip_bf16.h>
#include <math.h>

// TransitionLoss on MI355X (gfx950).
// Masks partition the 256 columns per anchor; tr[r,c] needed only for r,c in R
// with inner sum over K; sim is symmetric so one gathered S = sim[R x K] feeds
// both masked softmaxes (row-softmax -> ea, col-softmax transposed -> eb).

constexpr int kB  = 256;
constexpr int kD  = 512;
constexpr int kNT = 512;                  // 8 waves per anchor block

constexpr int SA_CAP = 17536;             // floats (valid max ~17292 + A-read slack)
constexpr int EB_CAP = 17472;             // floats (valid max ~16768 + B-read slack)
constexpr float NEG_BIG = -3.4e38f;

constexpr int SMEM_FLOATS = SA_CAP + EB_CAP + 4 * 256 + 16;
constexpr int SMEM_BYTES  = SMEM_FLOATS * 4 + 2048 + 256 + 16 + 4 + 12; // 146528

// ---------------- sim = f @ f^T, 16x16 tiles, b128 LDS reads ----------------
__global__ __launch_bounds__(256)
void simKernel(const float* __restrict__ f, float* __restrict__ sim) {
  __shared__ float As[16][68];
  __shared__ float Bs[16][68];
  const int tid = threadIdx.x;
  const int tx = tid & 15, ty = tid >> 4;
  const int lr = tid >> 4, lc4 = (tid & 15) * 4;
  const int rowBase = blockIdx.y * 16, colBase = blockIdx.x * 16;
  float acc = 0.f;
  for (int k0 = 0; k0 < kD; k0 += 64) {
    float4 va = *(const float4*)&f[(rowBase + lr) * kD + k0 + lc4];
    float4 vb = *(const float4*)&f[(colBase + lr) * kD + k0 + lc4];
    *(float4*)&As[lr][lc4] = va;
    *(float4*)&Bs[lr][lc4] = vb;
    __syncthreads();
#pragma unroll
    for (int kk = 0; kk < 64; kk += 4) {
      float4 a = *(const float4*)&As[ty][kk];
      float4 b = *(const float4*)&Bs[tx][kk];
      acc = fmaf(a.x, b.x, acc); acc = fmaf(a.y, b.y, acc);
      acc = fmaf(a.z, b.z, acc); acc = fmaf(a.w, b.w, acc);
    }
    __syncthreads();
  }
  sim[(rowBase + ty) * kB + colBase + tx] = acc;
}

// ---------------- matmul bodies ----------------
// pass1: rows < 128 (tyg = tid>>4 owns rows 4*tyg..+3), cols c0 + 64*t + 4*tx.
template <int NT>
__device__ __forceinline__ float mmPass1(const float* __restrict__ Sa,
                                         const float* __restrict__ Eb,
                                         int SK, int SR, int nR, int nKq,
                                         int c0, int tx, int tyg, int part) {
  const int rbase = tyg * 4;
  if (rbase >= nR) return 0.f;
  float acc[4][NT * 4];
#pragma unroll
  for (int j = 0; j < 4; j++)
#pragma unroll
    for (int q = 0; q < NT * 4; q++) acc[j][q] = 0.f;

  const float* a0 = Sa + rbase * SK;
  const float* a1 = a0 + SK;
  const float* a2 = a1 + SK;
  const float* a3 = a2 + SK;
  const float* bRow = Eb + c0 + tx * 4;
  for (int kq = 0; kq < nKq; kq++) {
    float4 av0 = *(const float4*)a0;
    float4 av1 = *(const float4*)a1;
    float4 av2 = *(const float4*)a2;
    float4 av3 = *(const float4*)a3;
#pragma unroll
    for (int kk = 0; kk < 4; kk++) {
      float4 b[NT];
#pragma unroll
      for (int t = 0; t < NT; t++) b[t] = *(const float4*)(bRow + t * 64);
      const float aj0 = (&av0.x)[kk];
      const float aj1 = (&av1.x)[kk];
      const float aj2 = (&av2.x)[kk];
      const float aj3 = (&av3.x)[kk];
#pragma unroll
      for (int t = 0; t < NT; t++) {
        acc[0][t*4+0] = fmaf(aj0, b[t].x, acc[0][t*4+0]);
        acc[0][t*4+1] = fmaf(aj0, b[t].y, acc[0][t*4+1]);
        acc[0][t*4+2] = fmaf(aj0, b[t].z, acc[0][t*4+2]);
        acc[0][t*4+3] = fmaf(aj0, b[t].w, acc[0][t*4+3]);
        acc[1][t*4+0] = fmaf(aj1, b[t].x, acc[1][t*4+0]);
        acc[1][t*4+1] = fmaf(aj1, b[t].y, acc[1][t*4+1]);
        acc[1][t*4+2] = fmaf(aj1, b[t].z, acc[1][t*4+2]);
        acc[1][t*4+3] = fmaf(aj1, b[t].w, acc[1][t*4+3]);
        acc[2][t*4+0] = fmaf(aj2, b[t].x, acc[2][t*4+0]);
        acc[2][t*4+1] = fmaf(aj2, b[t].y, acc[2][t*4+1]);
        acc[2][t*4+2] = fmaf(aj2, b[t].z, acc[2][t*4+2]);
        acc[2][t*4+3] = fmaf(aj2, b[t].w, acc[2][t*4+3]);
        acc[3][t*4+0] = fmaf(aj3, b[t].x, acc[3][t*4+0]);
        acc[3][t*4+1] = fmaf(aj3, b[t].y, acc[3][t*4+1]);
        acc[3][t*4+2] = fmaf(aj3, b[t].z, acc[3][t*4+2]);
        acc[3][t*4+3] = fmaf(aj3, b[t].w, acc[3][t*4+3]);
      }
      bRow += SR;
    }
    a0 += 4; a1 += 4; a2 += 4; a3 += 4;
  }
  float partSum = 0.f;
#pragma unroll
  for (int j = 0; j < 4; j++) {
    if (rbase + j < nR) {
#pragma unroll
      for (int t = 0; t < NT; t++) {
#pragma unroll
        for (int jj = 0; jj < 4; jj++) {
          int cc = c0 + t * 64 + tx * 4 + jj;
          if (cc < nR) {
            float x = sqrtf(fmaxf(acc[j][t*4+jj], 1e-12f));
            partSum += (part == 0) ? fmaxf(x - 0.2f, 0.f) : fmaxf(0.5f - x, 0.f);
          }
        }
      }
    }
  }
  return partSum;
}

// pass2: residual rows r0..r0+31 (wave = tid>>6 owns 4 rows), cols 4*(tid&63) (256 wide).
__device__ __forceinline__ float mmPass2(const float* __restrict__ Sa,
                                         const float* __restrict__ Eb,
                                         int SK, int SR, int nR, int nKq,
                                         int r0, int tid, int part) {
  const int ty2 = tid >> 6;
  const int tx2 = tid & 63;
  const int rbase = r0 + ty2 * 4;
  if (rbase >= nR) return 0.f;
  float acc[4][4];
#pragma unroll
  for (int j = 0; j < 4; j++)
#pragma unroll
    for (int q = 0; q < 4; q++) acc[j][q] = 0.f;

  const float* a0 = Sa + rbase * SK;
  const float* a1 = a0 + SK;
  const float* a2 = a1 + SK;
  const float* a3 = a2 + SK;
  const float* bRow = Eb + tx2 * 4;
  for (int kq = 0; kq < nKq; kq++) {
    float4 av0 = *(const float4*)a0;
    float4 av1 = *(const float4*)a1;
    float4 av2 = *(const float4*)a2;
    float4 av3 = *(const float4*)a3;
#pragma unroll
    for (int kk = 0; kk < 4; kk++) {
      float4 b = *(const float4*)bRow;
      const float aj0 = (&av0.x)[kk];
      const float aj1 = (&av1.x)[kk];
      const float aj2 = (&av2.x)[kk];
      const float aj3 = (&av3.x)[kk];
      acc[0][0] = fmaf(aj0, b.x, acc[0][0]); acc[0][1] = fmaf(aj0, b.y, acc[0][1]);
      acc[0][2] = fmaf(aj0, b.z, acc[0][2]); acc[0][3] = fmaf(aj0, b.w, acc[0][3]);
      acc[1][0] = fmaf(aj1, b.x, acc[1][0]); acc[1][1] = fmaf(aj1, b.y, acc[1][1]);
      acc[1][2] = fmaf(aj1, b.z, acc[1][2]); acc[1][3] = fmaf(aj1, b.w, acc[1][3]);
      acc[2][0] = fmaf(aj2, b.x, acc[2][0]); acc[2][1] = fmaf(aj2, b.y, acc[2][1]);
      acc[2][2] = fmaf(aj2, b.z, acc[2][2]); acc[2][3] = fmaf(aj2, b.w, acc[2][3]);
      acc[3][0] = fmaf(aj3, b.x, acc[3][0]); acc[3][1] = fmaf(aj3, b.y, acc[3][1]);
      acc[3][2] = fmaf(aj3, b.z, acc[3][2]); acc[3][3] = fmaf(aj3, b.w, acc[3][3]);
      bRow += SR;
    }
    a0 += 4; a1 += 4; a2 += 4; a3 += 4;
  }
  float partSum = 0.f;
#pragma unroll
  for (int j = 0; j < 4; j++) {
    if (rbase + j < nR) {
#pragma unroll
      for (int jj = 0; jj < 4; jj++) {
        int cc = tx2 * 4 + jj;
        if (cc < nR) {
          float x = sqrtf(fmaxf(acc[j][jj], 1e-12f));
          partSum += (part == 0) ? fmaxf(x - 0.2f, 0.f) : fmaxf(0.5f - x, 0.f);
        }
      }
    }
  }
  return partSum;
}

// ---------------- per-anchor loss ----------------
__global__ __launch_bounds__(kNT)
void anchorKernel(const float* __restrict__ sim, const int* __restrict__ subv,
                  const int* __restrict__ tgtv, float* __restrict__ lossPer) {
  extern __shared__ float smem[];
  float* Sa = smem;                  // S then ea in place, stride SK (SK%8==4)
  float* Eb = Sa + SA_CAP;           // eb[k][c], stride SR (SR%4==0)
  float* rm = Eb + EB_CAP;
  float* rs = rm + 256;
  float* cm = rs + 256;
  float* cs = cm + 256;
  float* red = cs + 256;
  unsigned short* idx = (unsigned short*)(red + 16);   // [4][256]
  unsigned char* catL = (unsigned char*)(idx + 1024);  // [256]
  int* cnt = (int*)(catL + 256);                       // [4]
  float* lossAcc = (float*)(cnt + 4);

  const int i = blockIdx.x;
  const int tid = threadIdx.x;
  const int lane = tid & 63;
  const int wave = tid >> 6;

  const int ti = tgtv[i];
  const int si = subv[i];

  if (tid < kB) {
    bool pos = (tgtv[tid] == ti);
    bool intra = (subv[tid] == si);
    catL[tid] = (unsigned char)(pos ? (intra ? 0 : 1) : (intra ? 2 : 3)); // mpi mpc mni mnc
  }
  if (tid == 0) *lossAcc = 0.f;
  __syncthreads();

  if (wave < 4) {  // ballot-compaction: wave w builds ascending list for category w
    int base = 0;
    for (int chunk = 0; chunk < 4; chunk++) {
      int c = (chunk << 6) + lane;
      bool fl = (catL[c] == (unsigned char)wave);
      unsigned long long m = __ballot(fl);
      if (fl) {
        int p = __popcll(m & ((1ull << lane) - 1ull));
        idx[(wave << 8) + base + p] = (unsigned short)c;
      }
      base += __popcll(m);
    }
    if (lane == 0) cnt[wave] = base;
  }
  __syncthreads();

  for (int part = 0; part < 2; part++) {
    // part 0: neg R=mni K=mnc f=relu(x-0.2); part 1: pos R=mpi K=mpc f=relu(0.5-x)
    const unsigned short* idxR = (part == 0) ? (idx + 512) : idx;
    const unsigned short* idxK = (part == 0) ? (idx + 768) : (idx + 256);
    const int nR = (part == 0) ? cnt[2] : cnt[0];
    const int nK = (part == 0) ? cnt[3] : cnt[1];
    if (nR == 0) continue;  // uniform

    const int nK4 = (nK + 3) & ~3;
    const int nKq = nK4 >> 2;
    int SK = nK4 < 4 ? 4 : nK4; if ((SK & 7) == 0) SK += 4;  // %8==4 -> A-reads 2-way
    const int SR = ((nR + 3) & ~3) < 4 ? 4 : ((nR + 3) & ~3);

    // gather S[r][k] = sim[idxR[r], idxK[k]]; pad cols [nK,nK4) with NEG_BIG
    for (int r = wave; r < nR; r += 8) {
      const float* srow = sim + (int)idxR[r] * kB;
      float* drow = Sa + r * SK;
      for (int k = lane; k < nK4; k += 64)
        drow[k] = (k < nK) ? srow[(int)idxK[k]] : NEG_BIG;
    }
    __syncthreads();

    if (nK > 0) {
      // row stats: wave per row, b128 quad reads, 2 passes (pad -> exp 0)
      for (int r = wave; r < nR; r += 8) {
        const float4* row4 = (const float4*)(Sa + r * SK);
        float m = NEG_BIG;
        for (int q = lane; q < nKq; q += 64) {
          float4 v = row4[q];
          m = fmaxf(fmaxf(m, fmaxf(v.x, v.y)), fmaxf(v.z, v.w));
        }
#pragma unroll
        for (int o = 32; o >= 1; o >>= 1) m = fmaxf(m, __shfl_xor(m, o, 64));
        float s = 0.f;
        for (int q = lane; q < nKq; q += 64) {
          float4 v = row4[q];
          s += __expf(v.x - m) + __expf(v.y - m) + __expf(v.z - m) + __expf(v.w - m);
        }
#pragma unroll
        for (int o = 32; o >= 1; o >>= 1) s += __shfl_xor(s, o, 64);
        if (lane == 0) { rm[r] = m; rs[r] = 1.f / s; }
      }
      // col stats: wave per k-quad, lane-local online (m,s) over b128 rows, merge
      for (int kq = wave; kq < nKq; kq += 8) {
        float m0 = NEG_BIG, m1 = NEG_BIG, m2 = NEG_BIG, m3 = NEG_BIG;
        float s0 = 0.f, s1 = 0.f, s2 = 0.f, s3 = 0.f;
        for (int c = lane; c < nR; c += 64) {
          float4 v = *(const float4*)(Sa + c * SK + kq * 4);
          float n0 = fmaxf(m0, v.x); s0 = s0 * __expf(m0 - n0) + __expf(v.x - n0); m0 = n0;
          float n1 = fmaxf(m1, v.y); s1 = s1 * __expf(m1 - n1) + __expf(v.y - n1); m1 = n1;
          float n2 = fmaxf(m2, v.z); s2 = s2 * __expf(m2 - n2) + __expf(v.z - n2); m2 = n2;
          float n3 = fmaxf(m3, v.w); s3 = s3 * __expf(m3 - n3) + __expf(v.w - n3); m3 = n3;
        }
#pragma unroll
        for (int o = 32; o >= 1; o >>= 1) {
          float om, os;
          om = __shfl_xor(m0, o, 64); os = __shfl_xor(s0, o, 64);
          { float n = fmaxf(m0, om); s0 = s0 * __expf(m0 - n) + os * __expf(om - n); m0 = n; }
          om = __shfl_xor(m1, o, 64); os = __shfl_xor(s1, o, 64);
          { float n = fmaxf(m1, om); s1 = s1 * __expf(m1 - n) + os * __expf(om - n); m1 = n; }
          om = __shfl_xor(m2, o, 64); os = __shfl_xor(s2, o, 64);
          { float n = fmaxf(m2, om); s2 = s2 * __expf(m2 - n) + os * __expf(om - n); m2 = n; }
          om = __shfl_xor(m3, o, 64); os = __shfl_xor(s3, o, 64);
          { float n = fmaxf(m3, om); s3 = s3 * __expf(m3 - n) + os * __expf(om - n); m3 = n; }
        }
        if (lane == 0) {
          int k = kq * 4;
          cm[k+0] = m0; cs[k+0] = 1.f / s0;
          cm[k+1] = m1; cs[k+1] = 1.f / s1;
          cm[k+2] = m2; cs[k+2] = 1.f / s2;
          cm[k+3] = m3; cs[k+3] = 1.f / s3;
        }
      }
      __syncthreads();

      // eb[k][c] = exp(S[c][k]-cm[k]) * cs[k]
      for (int k = wave; k < nK; k += 8) {
        const float mmv = cm[k], ssv = cs[k];
        float* erow = Eb + k * SR;
        for (int c = lane; c < nR; c += 64)
          erow[c] = __expf(Sa[c * SK + k] - mmv) * ssv;
      }
      // zero pad rows [nK,nK4) for all cols read by matmul (<=256)
      {
        const int padK = nK4 - nK;
        for (int e = tid; e < padK * 256; e += kNT) {
          int k = nK + (e >> 8), c = e & 255;
          Eb[k * SR + c] = 0.f;
        }
      }
      __syncthreads();

      // ea in place: Sa[r][k] -> exp(.-rm)*rs  (pad cols become exactly 0)
      for (int r = wave; r < nR; r += 8) {
        const float mmv = rm[r], ssv = rs[r];
        float4* row4 = (float4*)(Sa + r * SK);
        for (int q = lane; q < nKq; q += 64) {
          float4 v = row4[q];
          v.x = __expf(v.x - mmv) * ssv;
          v.y = __expf(v.y - mmv) * ssv;
          v.z = __expf(v.z - mmv) * ssv;
          v.w = __expf(v.w - mmv) * ssv;
          row4[q] = v;
        }
      }
      __syncthreads();
    }

    // tr = ea @ eb; f(sqrt(clip(tr,1e-12))) summed
    float partSum = 0.f;
    {
      const int tx = tid & 15, tyg = tid >> 4;
      for (int c0 = 0; c0 < nR; c0 += 192) {
        if (nR <= 64)       partSum += mmPass1<1>(Sa, Eb, SK, SR, nR, nKq, c0, tx, tyg, part);
        else if (nR <= 128) partSum += mmPass1<2>(Sa, Eb, SK, SR, nR, nKq, c0, tx, tyg, part);
        else                partSum += mmPass1<3>(Sa, Eb, SK, SR, nR, nKq, c0, tx, tyg, part);
      }
      for (int r0 = 128; r0 < nR; r0 += 32)
        partSum += mmPass2(Sa, Eb, SK, SR, nR, nKq, r0, tid, part);
    }

#pragma unroll
    for (int o = 1; o < 64; o <<= 1) partSum += __shfl_xor(partSum, o, 64);
    if (lane == 0) red[wave] = partSum;
    __syncthreads();
    if (tid == 0) {
      float t = 0.f;
      for (int w = 0; w < kNT / 64; w++) t += red[w];
      *lossAcc += t / ((float)nR * (float)nR);
    }
    __syncthreads();
  }
  if (tid == 0) lossPer[i] = *lossAcc;
}

// ---------------- deterministic final reduce ----------------
__global__ void reduceKernel(const float* __restrict__ lossPer, float* __restrict__ out) {
  const int tid = threadIdx.x;
  float v = lossPer[tid];
#pragma unroll
  for (int o = 1; o < 64; o <<= 1) v += __shfl_xor(v, o, 64);
  __shared__ float r4[4];
  if ((tid & 63) == 0) r4[tid >> 6] = v;
  __syncthreads();
  if (tid == 0) out[0] = (r4[0] + r4[1] + r4[2] + r4[3]) * (1.0f / 256.0f);
}

extern "C" void kernel_launch(void* const* d_in, const int* in_sizes, int n_in,
                              void* d_out, int out_size, void* d_ws, size_t ws_size,
                              hipStream_t stream) {
  (void)in_sizes; (void)n_in; (void)out_size; (void)ws_size;
  const float* feature = (const float*)d_in[0];
  const int* subv = (const int*)d_in[1];
  const int* tgtv = (const int*)d_in[2];
  float* out = (float*)d_out;
  float* sim = (float*)d_ws;
  float* lossPer = sim + kB * kB;

  (void)hipFuncSetAttribute(reinterpret_cast<const void*>(anchorKernel),
                            hipFuncAttributeMaxDynamicSharedMemorySize, SMEM_BYTES);

  simKernel<<<dim3(16, 16), 256, 0, stream>>>(feature, sim);
  anchorKernel<<<dim3(kB), kNT, SMEM_BYTES, stream>>>(sim, subv, tgtv, lossPer);
  reduceKernel<<<1, 256, 0, stream>>>(lossPer, out);
}

// Round 3
// 95.571 us; speedup vs baseline: 1.3202x; 1.2812x over previous
//
#include <hip/hip_runtime.h>
#include <hip/hip_bf16.h>
#include <math.h>

// TransitionLoss on MI355X (gfx950), v3.
// ln tr[r,c] = alpha[r] + w[c] + ln G[r,c],  G = X X^T (Gram, fp16, MFMA),
// X[a,k] = exp(S[a,k] - q[k] - w[a]), q[k] = (cm[k] + ln s_col[k])/2,
// alpha = w - rm - ln s_row. One matrix per part instead of ea+eb; log-space
// eval is overflow-safe (sim entries reach ~±100).

constexpr int kB = 256;
constexpr int kD = 512;
constexpr int kNT = 1024;                 // 16 waves: 4 waves/SIMD at 1 block/CU
constexpr float NEG_BIG = -3.4e38f;

typedef _Float16 f16x8 __attribute__((ext_vector_type(8)));
typedef _Float16 f16x4 __attribute__((ext_vector_type(4)));
typedef float f32x16 __attribute__((ext_vector_type(16)));

constexpr int S_CAP = 18432;   // f32 staging for S (both parts)
constexpr int X_CAP = 23808;   // fp16 X (both parts), stride 16m+8 (bank spread)
constexpr int SMEM_BYTES = S_CAP * 4 + 4 * 512 * 4 + 32 * 4 + X_CAP * 2
                         + 1024 * 2 + 256 + 16 + 16;  // = 132000

// ---------------- sim = f @ f^T (16x16 tiles, 4 indep accumulators) ----------
__global__ __launch_bounds__(256)
void simKernel(const float* __restrict__ f, float* __restrict__ sim) {
  __shared__ float As[16][68];
  __shared__ float Bs[16][68];
  const int tid = threadIdx.x;
  const int tx = tid & 15, ty = tid >> 4;
  const int lr = tid >> 4, lc4 = (tid & 15) * 4;
  const int rowBase = blockIdx.y * 16, colBase = blockIdx.x * 16;
  float a0 = 0.f, a1 = 0.f, a2 = 0.f, a3 = 0.f;
  for (int k0 = 0; k0 < kD; k0 += 64) {
    float4 va = *(const float4*)&f[(rowBase + lr) * kD + k0 + lc4];
    float4 vb = *(const float4*)&f[(colBase + lr) * kD + k0 + lc4];
    *(float4*)&As[lr][lc4] = va;
    *(float4*)&Bs[lr][lc4] = vb;
    __syncthreads();
#pragma unroll
    for (int kk = 0; kk < 64; kk += 16) {
      float4 x0 = *(const float4*)&As[ty][kk];
      float4 y0 = *(const float4*)&Bs[tx][kk];
      a0 = fmaf(x0.x, y0.x, a0); a0 = fmaf(x0.y, y0.y, a0);
      a0 = fmaf(x0.z, y0.z, a0); a0 = fmaf(x0.w, y0.w, a0);
      float4 x1 = *(const float4*)&As[ty][kk + 4];
      float4 y1 = *(const float4*)&Bs[tx][kk + 4];
      a1 = fmaf(x1.x, y1.x, a1); a1 = fmaf(x1.y, y1.y, a1);
      a1 = fmaf(x1.z, y1.z, a1); a1 = fmaf(x1.w, y1.w, a1);
      float4 x2 = *(const float4*)&As[ty][kk + 8];
      float4 y2 = *(const float4*)&Bs[tx][kk + 8];
      a2 = fmaf(x2.x, y2.x, a2); a2 = fmaf(x2.y, y2.y, a2);
      a2 = fmaf(x2.z, y2.z, a2); a2 = fmaf(x2.w, y2.w, a2);
      float4 x3 = *(const float4*)&As[ty][kk + 12];
      float4 y3 = *(const float4*)&Bs[tx][kk + 12];
      a3 = fmaf(x3.x, y3.x, a3); a3 = fmaf(x3.y, y3.y, a3);
      a3 = fmaf(x3.z, y3.z, a3); a3 = fmaf(x3.w, y3.w, a3);
    }
    __syncthreads();
  }
  sim[(rowBase + ty) * kB + colBase + tx] = (a0 + a1) + (a2 + a3);
}

// ---------------- per-anchor loss ----------------
__global__ __launch_bounds__(kNT)
void anchorKernel(const float* __restrict__ sim, const int* __restrict__ subv,
                  const int* __restrict__ tgtv, float* __restrict__ lossPer) {
  extern __shared__ float smem[];
  float* Sf  = smem;             // S staging, stride SK (mult4, %8==4)
  float* alA = Sf + S_CAP;       // rm during P1/P3, then alpha   [2][256]
  float* lsA = alA + 512;        // ln s_row                      [2][256]
  float* qA  = lsA + 512;        // q[k]                          [2][256]
  float* wA  = qA + 512;         // w[r]                          [2][256]
  float* red = wA + 512;         // [32]
  _Float16* Xh = (_Float16*)(red + 32);                 // fp16 X, stride SKh=16m+8
  unsigned short* idx = (unsigned short*)(Xh + X_CAP);  // [4][256]
  unsigned char* catL = (unsigned char*)(idx + 1024);   // [256]
  int* cnt = (int*)(catL + 256);                        // [4]

  const int i = blockIdx.x;
  const int tid = threadIdx.x;
  const int lane = tid & 63;
  const int wave = tid >> 6;

  if (tid < kB) {
    bool pos = (tgtv[tid] == tgtv[i]);
    bool intra = (subv[tid] == subv[i]);
    catL[tid] = (unsigned char)(pos ? (intra ? 0 : 1) : (intra ? 2 : 3)); // mpi mpc mni mnc
  }
  __syncthreads();

  if (wave < 4) {  // ballot-compaction: wave w -> ascending list for category w
    int base = 0;
    for (int chunk = 0; chunk < 4; chunk++) {
      int c = (chunk << 6) + lane;
      bool fl = (catL[c] == (unsigned char)wave);
      unsigned long long mm = __ballot(fl);
      if (fl) {
        int pfx = __popcll(mm & ((1ull << lane) - 1ull));
        idx[(wave << 8) + base + pfx] = (unsigned short)c;
      }
      base += __popcll(mm);
    }
    if (lane == 0) cnt[wave] = base;
  }
  __syncthreads();

  // part 0: neg R=mni(2) K=mnc(3), f=relu(x-0.2); part 1: pos R=mpi(0) K=mpc(1), f=relu(0.5-x)
  const int nR_[2] = { cnt[2], cnt[0] };
  const int nK_[2] = { cnt[3], cnt[1] };
  int SK_[2], SKh_[2], Sof_[2], Xof_[2], nR32_[2];
  {
    int so = 0, xo = 0;
    for (int p = 0; p < 2; p++) {
      int nR = nR_[p], nK = nK_[p];
      int nK4 = (nK + 3) & ~3;
      int sk = nK4 < 4 ? 4 : nK4; if ((sk & 7) == 0) sk += 4;
      int skh = ((nK4 + 15) & ~15) + 8;      // 16m+8: b128-aligned rows, bank spread
      int r32 = (nR + 31) & ~31;
      SK_[p] = sk; SKh_[p] = skh; nR32_[p] = r32;
      Sof_[p] = so; Xof_[p] = xo;
      if (nR > 0 && nK > 0) { so += nR * sk; xo += r32 * skh; }
    }
  }

  // ---- P1: gather + row stats (values stay in registers for the reduction) ----
  for (int p = 0; p < 2; p++) {
    const int nR = nR_[p], nK = nK_[p];
    if (nR == 0 || nK == 0) continue;
    const int nK4 = (nK + 3) & ~3, SK = SK_[p];
    const unsigned short* iR = idx + (p == 0 ? 512 : 0);
    const unsigned short* iK = idx + (p == 0 ? 768 : 256);
    int kIdx[4];
#pragma unroll
    for (int t = 0; t < 4; t++) {
      int k = lane + 64 * t;
      kIdx[t] = (k < nK) ? (int)iK[k] : 0;
    }
    float* Sp = Sf + Sof_[p];
    for (int j = wave; j < nR; j += 16) {
      const float* srow = sim + (int)iR[j] * kB;
      float v[4];
      float m = NEG_BIG;
#pragma unroll
      for (int t = 0; t < 4; t++) {
        int k = lane + 64 * t;
        float x = NEG_BIG;
        if (k < nK) x = srow[kIdx[t]];
        v[t] = x;
        if (k < nK4) Sp[j * SK + k] = x;
        m = fmaxf(m, x);
      }
#pragma unroll
      for (int o = 32; o >= 1; o >>= 1) m = fmaxf(m, __shfl_xor(m, o, 64));
      float s = 0.f;
#pragma unroll
      for (int t = 0; t < 4; t++) s += __expf(v[t] - m);  // pad -> exp(-3.4e38)=0
#pragma unroll
      for (int o = 32; o >= 1; o >>= 1) s += __shfl_xor(s, o, 64);
      if (lane == 0) { alA[p * 256 + j] = m; lsA[p * 256 + j] = __logf(s); }
    }
  }
  __syncthreads();

  // ---- P2: col stats -> q[k] = 0.5*(cm + ln s_col) ----
  for (int p = 0; p < 2; p++) {
    const int nR = nR_[p], nK = nK_[p];
    if (nR == 0 || nK == 0) continue;
    const int nK4 = (nK + 3) & ~3, nKq = nK4 >> 2, SK = SK_[p];
    const float* Sp = Sf + Sof_[p];
    for (int kq = wave; kq < nKq; kq += 16) {
      float m0 = NEG_BIG, m1 = NEG_BIG, m2 = NEG_BIG, m3 = NEG_BIG;
      for (int c = lane; c < nR; c += 64) {
        float4 vv = *(const float4*)(Sp + c * SK + kq * 4);
        m0 = fmaxf(m0, vv.x); m1 = fmaxf(m1, vv.y);
        m2 = fmaxf(m2, vv.z); m3 = fmaxf(m3, vv.w);
      }
#pragma unroll
      for (int o = 32; o >= 1; o >>= 1) {
        m0 = fmaxf(m0, __shfl_xor(m0, o, 64)); m1 = fmaxf(m1, __shfl_xor(m1, o, 64));
        m2 = fmaxf(m2, __shfl_xor(m2, o, 64)); m3 = fmaxf(m3, __shfl_xor(m3, o, 64));
      }
      float s0 = 0.f, s1 = 0.f, s2 = 0.f, s3 = 0.f;
      for (int c = lane; c < nR; c += 64) {
        float4 vv = *(const float4*)(Sp + c * SK + kq * 4);
        s0 += __expf(vv.x - m0); s1 += __expf(vv.y - m1);
        s2 += __expf(vv.z - m2); s3 += __expf(vv.w - m3);
      }
#pragma unroll
      for (int o = 32; o >= 1; o >>= 1) {
        s0 += __shfl_xor(s0, o, 64); s1 += __shfl_xor(s1, o, 64);
        s2 += __shfl_xor(s2, o, 64); s3 += __shfl_xor(s3, o, 64);
      }
      if (lane == 0) {
        float* qp = qA + p * 256 + kq * 4;
        qp[0] = 0.5f * (m0 + __logf(s0));
        qp[1] = 0.5f * (m1 + __logf(s1));
        qp[2] = 0.5f * (m2 + __logf(s2));
        qp[3] = 0.5f * (m3 + __logf(s3));
      }
    }
  }
  __syncthreads();

  // ---- P3: X = fp16(exp(S - q - w)), w = row max; alpha = w - rm - ln s_row ----
  for (int p = 0; p < 2; p++) {
    const int nR = nR_[p], nK = nK_[p];
    if (nR == 0 || nK == 0) continue;
    const int nK4 = (nK + 3) & ~3, nKq = nK4 >> 2;
    const int SK = SK_[p], SKh = SKh_[p], SKh4 = SKh >> 2;
    const int nR32 = nR32_[p];
    const float* Sp = Sf + Sof_[p];
    _Float16* Xp = Xh + Xof_[p];
    const float* qp = qA + p * 256;
    f16x4 zz; zz[0] = zz[1] = zz[2] = zz[3] = (_Float16)0.f;
    for (int j = wave; j < nR32; j += 16) {
      const int q = lane;
      if (j < nR) {
        float e0 = NEG_BIG, e1 = NEG_BIG, e2 = NEG_BIG, e3 = NEG_BIG;
        if (q < nKq) {
          float4 vv = *(const float4*)(Sp + j * SK + q * 4);
          e0 = vv.x - qp[q * 4 + 0]; e1 = vv.y - qp[q * 4 + 1];
          e2 = vv.z - qp[q * 4 + 2]; e3 = vv.w - qp[q * 4 + 3];
        }
        float wj = fmaxf(fmaxf(e0, e1), fmaxf(e2, e3));
#pragma unroll
        for (int o = 32; o >= 1; o >>= 1) wj = fmaxf(wj, __shfl_xor(wj, o, 64));
        f16x4 xv = zz;
        if (q < nKq) {
          xv[0] = (_Float16)__expf(e0 - wj);
          xv[1] = (_Float16)__expf(e1 - wj);
          xv[2] = (_Float16)__expf(e2 - wj);
          xv[3] = (_Float16)__expf(e3 - wj);
        }
        for (int u = q; u < SKh4; u += 64)
          *(f16x4*)(Xp + j * SKh + u * 4) = (u == q) ? xv : zz;
        if (lane == 0) {
          float rmv = alA[p * 256 + j];
          alA[p * 256 + j] = wj - rmv - lsA[p * 256 + j];  // alpha
          wA[p * 256 + j] = wj;
        }
      } else {
        for (int u = q; u < SKh4; u += 64)
          *(f16x4*)(Xp + j * SKh + u * 4) = zz;
      }
    }
  }
  __syncthreads();

  // ---- P4: G = X X^T via MFMA 32x32x16_f16; log-space eval ----
  float ps0 = 0.f, ps1 = 0.f;
  {
    const int l31 = lane & 31, kg = lane >> 5;
    for (int p = 0; p < 2; p++) {
      const int nR = nR_[p], nK = nK_[p];
      if (nR == 0 || nK == 0) continue;
      const int SKh = SKh_[p], nT = nR32_[p] >> 5;
      const _Float16* Xp = Xh + Xof_[p];
      const float* alp = alA + p * 256;
      const float* wwp = wA + p * 256;
      for (int t = wave; t < nT * nT; t += 16) {
        const int tr0 = t / nT;
        const int r0 = tr0 << 5, c0 = (t - tr0 * nT) << 5;
        const _Float16* pa = Xp + (r0 + l31) * SKh + 8 * kg;
        const _Float16* pb = Xp + (c0 + l31) * SKh + 8 * kg;
        f32x16 acc;
#pragma unroll
        for (int g = 0; g < 16; g++) acc[g] = 0.f;
        for (int kb = 0; kb + 16 <= SKh; kb += 16) {
          f16x8 a = *(const f16x8*)(pa + kb);
          f16x8 b = *(const f16x8*)(pb + kb);
          acc = __builtin_amdgcn_mfma_f32_32x32x16_f16(a, b, acc, 0, 0, 0);
        }
        const int c = c0 + l31;
        const bool cok = (c < nR);
        const float wc = wwp[c];
        const int rbase = r0 + 4 * kg;
#pragma unroll
        for (int g = 0; g < 16; g++) {
          const int r = rbase + (g & 3) + ((g >> 2) << 3);  // C/D: col=l&31, row=(g&3)+8(g>>2)+4(l>>5)
          if (cok && r < nR) {
            float lt = alp[r] + wc + __logf(acc[g]);
            lt = fmaxf(lt, -27.6310211159f);               // ln(1e-12) clip
            float x = __expf(0.5f * lt);                   // sqrt(tr)
            if (p == 0) ps0 += fmaxf(x - 0.2f, 0.f);
            else        ps1 += fmaxf(0.5f - x, 0.f);
          }
        }
      }
    }
  }
#pragma unroll
  for (int o = 32; o >= 1; o >>= 1) {
    ps0 += __shfl_xor(ps0, o, 64);
    ps1 += __shfl_xor(ps1, o, 64);
  }
  if (lane == 0) { red[wave] = ps0; red[16 + wave] = ps1; }
  __syncthreads();
  if (tid == 0) {
    float t0 = 0.f, t1 = 0.f;
    for (int w2 = 0; w2 < 16; w2++) { t0 += red[w2]; t1 += red[16 + w2]; }
    float loss = 0.f;
    if (nR_[0] > 0 && nK_[0] > 0) loss += t0 / ((float)nR_[0] * (float)nR_[0]);
    // nK0==0: x=1e-6 -> relu(x-0.2)=0, contributes nothing
    if (nR_[1] > 0) {
      if (nK_[1] > 0) loss += t1 / ((float)nR_[1] * (float)nR_[1]);
      else loss += 0.5f - sqrtf(1e-12f);   // empty K: tr=0 -> x=1e-6
    }
    lossPer[i] = loss;
  }
}

// ---------------- deterministic final reduce ----------------
__global__ void reduceKernel(const float* __restrict__ lossPer, float* __restrict__ out) {
  const int tid = threadIdx.x;
  float v = lossPer[tid];
#pragma unroll
  for (int o = 1; o < 64; o <<= 1) v += __shfl_xor(v, o, 64);
  __shared__ float r4[4];
  if ((tid & 63) == 0) r4[tid >> 6] = v;
  __syncthreads();
  if (tid == 0) out[0] = (r4[0] + r4[1] + r4[2] + r4[3]) * (1.0f / 256.0f);
}

extern "C" void kernel_launch(void* const* d_in, const int* in_sizes, int n_in,
                              void* d_out, int out_size, void* d_ws, size_t ws_size,
                              hipStream_t stream) {
  (void)in_sizes; (void)n_in; (void)out_size; (void)ws_size;
  const float* feature = (const float*)d_in[0];
  const int* subv = (const int*)d_in[1];
  const int* tgtv = (const int*)d_in[2];
  float* out = (float*)d_out;
  float* sim = (float*)d_ws;            // 256*256 f32
  float* lossPer = sim + kB * kB;       // 256 f32

  (void)hipFuncSetAttribute(reinterpret_cast<const void*>(anchorKernel),
                            hipFuncAttributeMaxDynamicSharedMemorySize, SMEM_BYTES);

  simKernel<<<dim3(16, 16), 256, 0, stream>>>(feature, sim);
  anchorKernel<<<dim3(kB), kNT, SMEM_BYTES, stream>>>(sim, subv, tgtv, lossPer);
  reduceKernel<<<1, 256, 0, stream>>>(lossPer, out);
}